// Round 8
// baseline (53.804 us; speedup 1.0000x reference)
//
#include <hip/hip_runtime.h>
#include <hip/hip_bf16.h>

// LengthRegulator: x (B,S,D) f32, durations (B,S) int.
// dur = clip(dur,1,None); cum = cumsum(dur, axis=1); totals = cum[:,-1];
// out[b,p,:] = x[b, searchsorted_right(cum[b], p), :] for p < totals[b], else 0.
// Output (B, max_len, D), max_len = out_size/(B*D).
//
// Fused, 1024-thread blocks (16 waves), BPB=16 blocks per batch.
// Copy loop uses strided 4-row granules (wave wv owns granules wv*4 + 64*k)
// so only ONE wave per block touches the partial-granule tail, and the next
// granule's LDS idx reads are prefetched before the current stores.

constexpr int B = 32;
constexpr int S = 1024;
constexpr int D = 512;
constexpr int VEC = D / 4;               // 128 float4 per row
constexpr int BPB = 16;                  // blocks per batch
constexpr int NW  = 16;                  // waves per block (1024 threads)
constexpr int MAX_RPB = 320;             // rpb = ceil(max_len/16)

using f4 = __attribute__((ext_vector_type(4))) float;

__global__ __launch_bounds__(1024, 2)
void lr_fused(const int* __restrict__ durations,
              const f4* __restrict__ x4,
              f4* __restrict__ out,
              int max_len) {
    const int b   = blockIdx.x >> 4;     // batch
    const int blk = blockIdx.x & (BPB - 1);
    const int rpb = (max_len + BPB - 1) / BPB;
    const int p0  = blk * rpb;
    const int p1  = min(p0 + rpb, max_len);
    if (p0 >= p1) return;                // uniform across block

    const int t    = threadIdx.x;        // 0..1023
    const int lane = t & 63;
    const int wv   = t >> 6;             // 0..15

    __shared__ int wsum[NW];
    __shared__ int s_idx[MAX_RPB];

    // ---- scan of this batch's clipped durations, 1 elem/thread ----
    int d = durations[b * S + t];
    if (d < 1) d = 1;

    int inc = d;
    #pragma unroll
    for (int off = 1; off < 64; off <<= 1) {
        int n = __shfl_up(inc, off, 64);
        if (lane >= off) inc += n;
    }
    if (lane == 63) wsum[wv] = inc;

    const int nblk = p1 - p0;
    for (int q = t; q < nblk; q += 1024) s_idx[q] = -1;   // masked-tail default
    __syncthreads();

    int base = 0;
    #pragma unroll
    for (int j = 0; j < NW; ++j) if (j < wv) base += wsum[j];

    // ---- scatter source indices intersecting [p0, p1) into LDS ----
    const int pstart = base + inc - d;   // exclusive prefix
    const int pend   = pstart + d;
    const int src    = b * S + t;
    for (int q = max(pstart, p0); q < min(pend, p1); ++q) s_idx[q - p0] = src;
    __syncthreads();

    // ---- streaming copy: strided 4-row granules ----
    f4* __restrict__ dbase = out + ((size_t)b * max_len + p0) * VEC;

    int rg = wv * 4;
    int i0 = 0, i1 = 0, i2 = 0, i3 = 0;
    if (rg + 4 <= nblk) {                // prefetch first granule's indices
        i0 = s_idx[rg]; i1 = s_idx[rg + 1]; i2 = s_idx[rg + 2]; i3 = s_idx[rg + 3];
    }

    while (rg + 4 <= nblk) {
        const int j0 = __builtin_amdgcn_readfirstlane(i0);
        const int j1 = __builtin_amdgcn_readfirstlane(i1);
        const int j2 = __builtin_amdgcn_readfirstlane(i2);
        const int j3 = __builtin_amdgcn_readfirstlane(i3);

        f4 a0 = {0,0,0,0}, c0 = {0,0,0,0};
        f4 a1 = {0,0,0,0}, c1 = {0,0,0,0};
        f4 a2 = {0,0,0,0}, c2 = {0,0,0,0};
        f4 a3 = {0,0,0,0}, c3 = {0,0,0,0};
        if (j0 >= 0) { const f4* s = x4 + (size_t)j0 * VEC; a0 = s[lane]; c0 = s[lane + 64]; }
        if (j1 >= 0) { const f4* s = x4 + (size_t)j1 * VEC; a1 = s[lane]; c1 = s[lane + 64]; }
        if (j2 >= 0) { const f4* s = x4 + (size_t)j2 * VEC; a2 = s[lane]; c2 = s[lane + 64]; }
        if (j3 >= 0) { const f4* s = x4 + (size_t)j3 * VEC; a3 = s[lane]; c3 = s[lane + 64]; }

        const int rn = rg + NW * 4;      // next granule for this wave
        if (rn + 4 <= nblk) {            // prefetch its indices before stores
            i0 = s_idx[rn]; i1 = s_idx[rn + 1]; i2 = s_idx[rn + 2]; i3 = s_idx[rn + 3];
        }

        f4* __restrict__ dst = dbase + (size_t)rg * VEC;
        __builtin_nontemporal_store(a0, dst + lane);
        __builtin_nontemporal_store(c0, dst + lane + 64);
        __builtin_nontemporal_store(a1, dst + VEC + lane);
        __builtin_nontemporal_store(c1, dst + VEC + lane + 64);
        __builtin_nontemporal_store(a2, dst + 2 * VEC + lane);
        __builtin_nontemporal_store(c2, dst + 2 * VEC + lane + 64);
        __builtin_nontemporal_store(a3, dst + 3 * VEC + lane);
        __builtin_nontemporal_store(c3, dst + 3 * VEC + lane + 64);

        rg = rn;
    }
    // partial granule: exactly one wave per block lands here (<=3 rows)
    for (int r = rg; r < nblk; ++r) {
        const int j = __builtin_amdgcn_readfirstlane(s_idx[r]);
        f4 a = {0,0,0,0}, c = {0,0,0,0};
        if (j >= 0) { const f4* s = x4 + (size_t)j * VEC; a = s[lane]; c = s[lane + 64]; }
        f4* __restrict__ dst = dbase + (size_t)r * VEC;
        __builtin_nontemporal_store(a, dst + lane);
        __builtin_nontemporal_store(c, dst + lane + 64);
    }
}

extern "C" void kernel_launch(void* const* d_in, const int* in_sizes, int n_in,
                              void* d_out, int out_size, void* d_ws, size_t ws_size,
                              hipStream_t stream) {
    const float* x = (const float*)d_in[0];
    const int* durations = (const int*)d_in[1];
    float* out = (float*)d_out;

    const int max_len = out_size / (B * D);

    lr_fused<<<B * BPB, 1024, 0, stream>>>(
        durations, (const f4*)x, (f4*)out, max_len);
}